// Round 4
// baseline (145.669 us; speedup 1.0000x reference)
//
#include <hip/hip_runtime.h>
#include <math.h>

// Fused soft-argmax centroid over [B,K,128,128] fp32, two inputs.
// 2048 blocks (= nunits) x 256 threads: exactly 8 blocks/CU, one generation,
// zero block turnover. Each thread: 16 float4, software-pipelined as two
// 4-deep batches (8 KB per wave in flight). Block reduces and writes its
// unit's (x,y) directly -- single kernel launch, no workspace.

#define HM_H 128
#define HM_W 128

__global__ __launch_bounds__(256) void centroid_fused(
    const float* __restrict__ hm0,
    const float* __restrict__ hm1,
    float* __restrict__ out,
    int BK)
{
    const int u  = blockIdx.x;                 // 0 .. 2*BK-1 (one unit per block)
    const int bk = (u >= BK) ? (u - BK) : u;
    const float* __restrict__ src =
        ((u >= BK) ? hm1 : hm0) + (size_t)bk * (HM_H * HM_W);
    const float4* __restrict__ p = (const float4*)src;
    const int t = threadIdx.x;

    const float colb = (float)((t << 2) & (HM_W - 1)); // column of lane's 4-group
    const float rowb = (float)(t >> 5);                // row within an 8-row slab

    float s = 0.0f, sx = 0.0f, sy = 0.0f;

    // batch J covers f4 indices t + (4J+m)*256, m=0..3 ; rows = rowb + 32J + 8m
#define ACC(V0, V1, V2, V3, J) do {                                        \
        const float s0 = V0.x + V0.y + V0.z + V0.w;                        \
        const float s1 = V1.x + V1.y + V1.z + V1.w;                        \
        const float s2 = V2.x + V2.y + V2.z + V2.w;                        \
        const float s3 = V3.x + V3.y + V3.z + V3.w;                        \
        const float st = s0 + s1 + s2 + s3;                                \
        s  += st;                                                          \
        sx += colb * st                                                    \
            + (V0.y + V1.y + V2.y + V3.y)                                  \
            + 2.0f * (V0.z + V1.z + V2.z + V3.z)                           \
            + 3.0f * (V0.w + V1.w + V2.w + V3.w);                          \
        sy += (rowb + (float)(32 * (J))) * st                              \
            + 8.0f * (s1 + 2.0f * s2 + 3.0f * s3);                         \
    } while (0)

    float4 A0, A1, A2, A3, B0, B1, B2, B3;
    A0 = p[t];          A1 = p[t +  256];  A2 = p[t +  512];  A3 = p[t +  768];
    B0 = p[t + 1024];   B1 = p[t + 1280];  B2 = p[t + 1536];  B3 = p[t + 1792];

    ACC(A0, A1, A2, A3, 0);
    A0 = p[t + 2048];   A1 = p[t + 2304];  A2 = p[t + 2560];  A3 = p[t + 2816];
    ACC(B0, B1, B2, B3, 1);
    B0 = p[t + 3072];   B1 = p[t + 3328];  B2 = p[t + 3584];  B3 = p[t + 3840];
    ACC(A0, A1, A2, A3, 2);
    ACC(B0, B1, B2, B3, 3);
#undef ACC

    // ---- wave (64-lane) butterfly reduce ----
#pragma unroll
    for (int off = 32; off > 0; off >>= 1) {
        s  += __shfl_down(s,  off, 64);
        sx += __shfl_down(sx, off, 64);
        sy += __shfl_down(sy, off, 64);
    }

    __shared__ float ls[4], lx[4], ly[4];
    const int wid  = t >> 6;
    const int lane = t & 63;
    if (lane == 0) { ls[wid] = s; lx[wid] = sx; ly[wid] = sy; }
    __syncthreads();

    if (t == 0) {
        const float S = ls[0] + ls[1] + ls[2] + ls[3];
        const float X = lx[0] + lx[1] + lx[2] + lx[3];
        const float Y = ly[0] + ly[1] + ly[2] + ly[3];
        // out = [keypoint (BK*2) | tf_keypoint (BK*2)]; u*2 indexes both halves
        out[u * 2 + 0] = rintf(X / S);   // round-half-to-even == jnp.round
        out[u * 2 + 1] = rintf(Y / S);
    }
}

extern "C" void kernel_launch(void* const* d_in, const int* in_sizes, int n_in,
                              void* d_out, int out_size, void* d_ws, size_t ws_size,
                              hipStream_t stream) {
    const float* hm0 = (const float*)d_in[0];
    const float* hm1 = (const float*)d_in[1];
    float* out = (float*)d_out;

    const int BK     = out_size / 4;   // B*K
    const int nunits = 2 * BK;         // 2048 blocks = 8 per CU, one generation

    centroid_fused<<<nunits, 256, 0, stream>>>(hm0, hm1, out, BK);
}

// Round 6
// 145.590 us; speedup vs baseline: 1.0005x; 1.0005x over previous
//
#include <hip/hip_runtime.h>
#include <math.h>

// Fused soft-argmax centroid over [B,K,128,128] fp32, two inputs.
// 2048 blocks x 256 threads, one generation. __launch_bounds__(256,2)
// lifts the VGPR cap so all 16 float4 loads per thread can be in flight
// BEFORE any accumulation (16 KB/wave MLP). 4 parallel accumulator trees.

#define HM_H 128
#define HM_W 128

__global__ __launch_bounds__(256, 2) void centroid_deep(
    const float* __restrict__ hm0,
    const float* __restrict__ hm1,
    float* __restrict__ out,
    int BK)
{
    const int u  = blockIdx.x;                 // 0 .. 2*BK-1
    const int bk = (u >= BK) ? (u - BK) : u;
    const float4* __restrict__ p =
        (const float4*)(((u >= BK) ? hm1 : hm0) + (size_t)bk * (HM_H * HM_W));
    const int t = threadIdx.x;

    // ---- issue ALL 16 loads first: 64 VGPRs of data in flight ----
    const float4 v0  = p[t];
    const float4 v1  = p[t +  256];
    const float4 v2  = p[t +  512];
    const float4 v3  = p[t +  768];
    const float4 v4  = p[t + 1024];
    const float4 v5  = p[t + 1280];
    const float4 v6  = p[t + 1536];
    const float4 v7  = p[t + 1792];
    const float4 v8  = p[t + 2048];
    const float4 v9  = p[t + 2304];
    const float4 v10 = p[t + 2560];
    const float4 v11 = p[t + 2816];
    const float4 v12 = p[t + 3072];
    const float4 v13 = p[t + 3328];
    const float4 v14 = p[t + 3584];
    const float4 v15 = p[t + 3840];

    const float colb = (float)((t << 2) & (HM_W - 1)); // column of lane's 4-group
    const float rowb = (float)(t >> 5);                // base row (load m adds 8m)

    // ---- 4 parallel accumulator trees (m = j, j+4, j+8, j+12) ----
#define SV(V) ((V).x + (V).y + (V).z + (V).w)
#define YZ(V) ((V).y + 2.0f * (V).z + 3.0f * (V).w)

    const float s0_0 = SV(v0),  s0_1 = SV(v4),  s0_2 = SV(v8),   s0_3 = SV(v12);
    const float s1_0 = SV(v1),  s1_1 = SV(v5),  s1_2 = SV(v9),   s1_3 = SV(v13);
    const float s2_0 = SV(v2),  s2_1 = SV(v6),  s2_2 = SV(v10),  s2_3 = SV(v14);
    const float s3_0 = SV(v3),  s3_1 = SV(v7),  s3_2 = SV(v11),  s3_3 = SV(v15);

    // per-tree sums
    const float t0 = s0_0 + s0_1 + s0_2 + s0_3;   // m = 0,4,8,12
    const float t1 = s1_0 + s1_1 + s1_2 + s1_3;   // m = 1,5,9,13
    const float t2 = s2_0 + s2_1 + s2_2 + s2_3;   // m = 2,6,10,14
    const float t3 = s3_0 + s3_1 + s3_2 + s3_3;   // m = 3,7,11,15

    const float s = (t0 + t1) + (t2 + t3);

    // sum m*sv over all 16: tree j contributes j*tj + 4*(1*s?_1 + 2*s?_2 + 3*s?_3)
    const float msum =
          (t1 + 2.0f * t2 + 3.0f * t3)
        + 4.0f * ( (s0_1 + s1_1 + s2_1 + s3_1)
          + 2.0f * (s0_2 + s1_2 + s2_2 + s3_2)
          + 3.0f * (s0_3 + s1_3 + s2_3 + s3_3) );

    const float yzsum =
          (YZ(v0)  + YZ(v1)  + YZ(v2)  + YZ(v3))
        + (YZ(v4)  + YZ(v5)  + YZ(v6)  + YZ(v7))
        + (YZ(v8)  + YZ(v9)  + YZ(v10) + YZ(v11))
        + (YZ(v12) + YZ(v13) + YZ(v14) + YZ(v15));

    float sx = colb * s + yzsum;
    float sy = rowb * s + 8.0f * msum;
#undef SV
#undef YZ

    // ---- wave (64-lane) butterfly reduce ----
    float ss = s;
#pragma unroll
    for (int off = 32; off > 0; off >>= 1) {
        ss += __shfl_down(ss, off, 64);
        sx += __shfl_down(sx, off, 64);
        sy += __shfl_down(sy, off, 64);
    }

    __shared__ float ls[4], lx[4], ly[4];
    const int wid  = t >> 6;
    const int lane = t & 63;
    if (lane == 0) { ls[wid] = ss; lx[wid] = sx; ly[wid] = sy; }
    __syncthreads();

    if (t == 0) {
        const float S = ls[0] + ls[1] + ls[2] + ls[3];
        const float X = lx[0] + lx[1] + lx[2] + lx[3];
        const float Y = ly[0] + ly[1] + ly[2] + ly[3];
        // out = [keypoint (BK*2) | tf_keypoint (BK*2)]
        out[u * 2 + 0] = rintf(X / S);   // round-half-to-even == jnp.round
        out[u * 2 + 1] = rintf(Y / S);
    }
}

extern "C" void kernel_launch(void* const* d_in, const int* in_sizes, int n_in,
                              void* d_out, int out_size, void* d_ws, size_t ws_size,
                              hipStream_t stream) {
    const float* hm0 = (const float*)d_in[0];
    const float* hm1 = (const float*)d_in[1];
    float* out = (float*)d_out;

    const int BK     = out_size / 4;   // B*K
    const int nunits = 2 * BK;         // 2048 blocks

    centroid_deep<<<nunits, 256, 0, stream>>>(hm0, hm1, out, BK);
}